// Round 3
// baseline (2419.238 us; speedup 1.0000x reference)
//
#include <hip/hip_runtime.h>
#include <hip/hip_bf16.h>
#include <math.h>

#define R 10
#define C 6
#define HID 128
#define HEADS 4
#define NL 3
#define KO 512            // HEADS*HID
#define TOK 1280          // R*HID
#define NCAT 544          // padded prep N: 512 xp + 8 logit cols
#define NTILES 33         // 32 xp tiles + 1 logit tile
#define NFS 136           // s_nfb row stride (shorts)
#define HS 132            // s_nf row stride (floats)
#define LN_EPS 1e-5f
#define NEG_SLOPE 0.2f
#define MAXE 40
#define MAXDEG 16

typedef __attribute__((ext_vector_type(8))) short short8v;  // 8 bf16 (x32 MFMA A/B)
typedef __attribute__((ext_vector_type(4))) short bf16x4;   // 4 bf16 (x16 MFMA A/B)
typedef __attribute__((ext_vector_type(4))) float floatx4;

__device__ __forceinline__ float gelu_exact(float v) {
    return 0.5f * v * (1.0f + erff(v * 0.70710678118654752440f));
}
__device__ __forceinline__ short f2bf(float v) {
    __hip_bfloat16 b = __float2bfloat16(v);
    return __builtin_bit_cast(short, b);
}

// ---- prep: Wcat[l][n][k] bf16, n-major k-contiguous ----
// n in [0,512): W^T columns; [512,516): W@asrc_h; [516,520): W@adst_h; rest 0.
__global__ void prep_wcat(const float* __restrict__ Wg,
                          const float* __restrict__ asrc,
                          const float* __restrict__ adst,
                          short* __restrict__ Wcat)
{
    int idx = blockIdx.x * 256 + threadIdx.x;
    const int TOTAL = NL * NCAT * HID;
    if (idx >= TOTAL) return;
    int k = idx & (HID - 1);
    int n = (idx >> 7) % NCAT;
    int l = idx / (NCAT * HID);
    float v = 0.f;
    if (n < KO) {
        v = Wg[((size_t)l * HID + k) * KO + n];
    } else if (n < KO + 8) {
        int h = (n - KO) & 3;
        const float* a = ((n - KO) < 4 ? asrc : adst) + (l * HEADS + h) * HID;
        const float* w = Wg + ((size_t)l * HID + k) * KO + h * HID;
        float s = 0.f;
        for (int f = 0; f < HID; ++f) s = fmaf(w[f], a[f], s);
        v = s;
    }
    Wcat[idx] = f2bf(v);
}

__global__ __launch_bounds__(256, 4) void fused_gnn_mfma2(
    const float* __restrict__ x,      // (BT, 60)
    const float* __restrict__ Wenc,   // (R, C, HID)
    const float* __restrict__ benc,   // (R, HID)
    const float* __restrict__ gamma_, // (R, HID)
    const float* __restrict__ beta_,  // (R, HID)
    const short* __restrict__ Wcat,   // (NL, NCAT, HID) bf16
    const float* __restrict__ bg,     // (NL, HID)
    const int* __restrict__ srce, const int* __restrict__ dste,
    float* __restrict__ gf_out, float* __restrict__ rf_out, int E)
{
    __shared__ __align__(16) short s_nfb[2 * 16 * NFS];        // 8.7 KB  bf16 nf, A-layout
    __shared__ __align__(16) float s_nf[2 * R * HS];           // 10.6 KB fp32 h / nf (residual source)
    __shared__ __align__(16) short s_amat[2 * HEADS * 16 * 16];// 4.1 KB  alpha matrices bf16
    __shared__ float s_logit[2 * 16 * 8];                      // 1.0 KB
    __shared__ float s_x[120];
    __shared__ float s_mu[20], s_rs[20];
    __shared__ int s_src[MAXE], s_dst[MAXE], s_eid[R * MAXDEG], s_deg[R];

    const int t = threadIdx.x;
    const int lane = t & 63;
    const int w = t >> 6;          // wave
    const int quad = lane >> 4;
    const int col = lane & 15;
    const int tok0 = blockIdx.x * 2;

    // ---- prologue: zero s_nfb (rows 10-15 must stay 0), stage x + edges ----
    for (int i = t; i < (2 * 16 * NFS) / 2; i += 256) ((int*)s_nfb)[i] = 0;
    if (t < E) { s_src[t] = srce[t]; s_dst[t] = dste[t]; }
    if (t < 120) s_x[t] = x[(size_t)tok0 * 60 + t];
    __syncthreads();
    if (t < R) {
        int d = 0;
        for (int e = 0; e < E; ++e)
            if (s_dst[e] == t && d < MAXDEG) s_eid[t * MAXDEG + (d++)] = e;
        s_deg[t] = d;
    }

    // ---- encoder: h = x @ Wenc + benc -> s_nf ----
    for (int q = t; q < 640; q += 256) {
        int tk = q >= 320; int qq = q - tk * 320;
        int r = qq >> 5; int f4 = (qq & 31) << 2;
        const float* xr = &s_x[tk * 60 + r * 6];
        float4 acc = *(const float4*)&benc[r * HID + f4];
        #pragma unroll
        for (int c = 0; c < 6; ++c) {
            float xv = xr[c];
            float4 wv = *(const float4*)&Wenc[(r * 6 + c) * HID + f4];
            acc.x = fmaf(xv, wv.x, acc.x);
            acc.y = fmaf(xv, wv.y, acc.y);
            acc.z = fmaf(xv, wv.z, acc.z);
            acc.w = fmaf(xv, wv.w, acc.w);
        }
        *(float4*)&s_nf[(tk * R + r) * HS + f4] = acc;
    }
    __syncthreads();

    // ---- LayerNorm stats ----
    for (int rr = w; rr < 20; rr += 4) {
        const float* row = &s_nf[rr * HS];
        float v0 = row[lane], v1 = row[lane + 64];
        float sum = v0 + v1, sq = v0 * v0 + v1 * v1;
        #pragma unroll
        for (int off = 32; off > 0; off >>= 1) {
            sum += __shfl_down(sum, off);
            sq  += __shfl_down(sq,  off);
        }
        if (lane == 0) {
            float mu = sum * (1.0f / HID);
            float var = sq * (1.0f / HID) - mu * mu;
            s_mu[rr] = mu;
            s_rs[rr] = rsqrtf(var + LN_EPS);
        }
    }
    __syncthreads();

    // ---- normalize + affine + gelu -> s_nf (in place), s_nfb, rf_out ----
    for (int q = t; q < 640; q += 256) {
        int tk = q >= 320; int qq = q - tk * 320;
        int r = qq >> 5; int f4 = (qq & 31) << 2;
        float4 v = *(const float4*)&s_nf[(tk * R + r) * HS + f4];
        float mu = s_mu[tk * R + r], rs = s_rs[tk * R + r];
        float4 g = *(const float4*)&gamma_[r * HID + f4];
        float4 b = *(const float4*)&beta_[r * HID + f4];
        float4 o;
        o.x = gelu_exact((v.x - mu) * rs * g.x + b.x);
        o.y = gelu_exact((v.y - mu) * rs * g.y + b.y);
        o.z = gelu_exact((v.z - mu) * rs * g.z + b.z);
        o.w = gelu_exact((v.w - mu) * rs * g.w + b.w);
        *(float4*)&s_nf[(tk * R + r) * HS + f4] = o;
        short4 pk; pk.x = f2bf(o.x); pk.y = f2bf(o.y); pk.z = f2bf(o.z); pk.w = f2bf(o.w);
        *(short4*)&s_nfb[(tk * 16 + r) * NFS + f4] = pk;
        *(float4*)&rf_out[(size_t)(tok0 + tk) * TOK + qq * 4] = o;
    }
    __syncthreads();

    // ---- residual fragments in registers: rows m=quad*4+j, cols f=(w+4s)*16+col ----
    float nf_frag[2][2][4];
    #pragma unroll
    for (int tk = 0; tk < 2; ++tk)
        #pragma unroll
        for (int s = 0; s < 2; ++s) {
            int f = (w + 4 * s) * 16 + col;
            #pragma unroll
            for (int j = 0; j < 4; ++j) {
                int m = quad * 4 + j;
                nf_frag[tk][s][j] = (m < R) ? s_nf[(tk * R + m) * HS + f] : 0.f;
            }
        }

    // ---- 3 GAT layers ----
    for (int l = 0; l < NL; ++l) {
        const short* __restrict__ Wl = Wcat + (size_t)l * NCAT * HID;

        // A fragments from s_nfb (A[m=lane&15][k=quad*8+j], k += 32/step)
        short8v aF[2][4];
        #pragma unroll
        for (int tk = 0; tk < 2; ++tk)
            #pragma unroll
            for (int ks = 0; ks < 4; ++ks)
                aF[tk][ks] = *(const short8v*)&s_nfb[(tk * 16 + col) * NFS + ks * 32 + quad * 8];

        // GEMM1: xp tiles kept in registers as bf16 (future MFMA2 B operands)
        bf16x4 Bb[2][8];
        int i = 0;
        for (int nt = w; nt < NTILES; nt += 4, ++i) {
            const short* Bp = Wl + (nt * 16 + col) * HID + quad * 8;
            short8v b0 = *(const short8v*)(Bp);
            short8v b1 = *(const short8v*)(Bp + 32);
            short8v b2 = *(const short8v*)(Bp + 64);
            short8v b3 = *(const short8v*)(Bp + 96);
            #pragma unroll
            for (int tk = 0; tk < 2; ++tk) {
                floatx4 c = {0.f, 0.f, 0.f, 0.f};
                c = __builtin_amdgcn_mfma_f32_16x16x32_bf16(aF[tk][0], b0, c, 0, 0, 0);
                c = __builtin_amdgcn_mfma_f32_16x16x32_bf16(aF[tk][1], b1, c, 0, 0, 0);
                c = __builtin_amdgcn_mfma_f32_16x16x32_bf16(aF[tk][2], b2, c, 0, 0, 0);
                c = __builtin_amdgcn_mfma_f32_16x16x32_bf16(aF[tk][3], b3, c, 0, 0, 0);
                if (nt < 32) {
                    bf16x4 pk;
                    pk[0] = f2bf(c[0]); pk[1] = f2bf(c[1]);
                    pk[2] = f2bf(c[2]); pk[3] = f2bf(c[3]);
                    Bb[tk][i] = pk;
                } else if (col < 8) {          // logit tile (cols 512-519)
                    #pragma unroll
                    for (int j = 0; j < 4; ++j) {
                        int m = quad * 4 + j;
                        if (m < R) s_logit[tk * 128 + m * 8 + col] = c[j];
                    }
                }
            }
        }
        __syncthreads();

        // ---- softmax -> alpha matrices (bf16, A-layout-ready row-major 16x16) ----
        if (t < 80) {
            int tk = t / 40; int rem = t - tk * 40;
            int r = rem >> 2; int h = rem & 3;
            short* arow = &s_amat[((tk * 4 + h) * 16 + r) * 16];
            #pragma unroll
            for (int k = 0; k < 16; ++k) arow[k] = 0;
            float ald = s_logit[tk * 128 + r * 8 + 4 + h];
            int d = s_deg[r];
            float m = -1e30f;
            for (int k = 0; k < d; ++k) {
                int e = s_eid[r * MAXDEG + k];
                float val = s_logit[tk * 128 + s_src[e] * 8 + h] + ald;
                val = (val > 0.f) ? val : NEG_SLOPE * val;
                m = fmaxf(m, val);
            }
            float ssum = 0.f;
            for (int k = 0; k < d; ++k) {
                int e = s_eid[r * MAXDEG + k];
                float val = s_logit[tk * 128 + s_src[e] * 8 + h] + ald;
                val = (val > 0.f) ? val : NEG_SLOPE * val;
                ssum += expf(val - m);
            }
            float inv = 1.0f / ssum;
            for (int k = 0; k < d; ++k) {
                int e = s_eid[r * MAXDEG + k];
                float val = s_logit[tk * 128 + s_src[e] * 8 + h] + ald;
                val = (val > 0.f) ? val : NEG_SLOPE * val;
                arow[s_src[e]] = f2bf(expf(val - m) * inv);
            }
        } else if (t < 128) {                 // zero alpha rows 10-15
            int idx = t - 80;                 // 0..47
            int tk = idx / 24; int rem = idx % 24;
            int h = rem / 6; int r = 10 + rem % 6;
            short* arow = &s_amat[((tk * 4 + h) * 16 + r) * 16];
            #pragma unroll
            for (int k = 0; k < 16; ++k) arow[k] = 0;
        }
        __syncthreads();

        // ---- MFMA2 aggregation (heads chained into one acc) + epilogue ----
        #pragma unroll
        for (int s = 0; s < 2; ++s) {
            int f = (w + 4 * s) * 16 + col;
            float bgv = bg[l * HID + f];
            #pragma unroll
            for (int tk = 0; tk < 2; ++tk) {
                floatx4 acc = {0.f, 0.f, 0.f, 0.f};
                #pragma unroll
                for (int h = 0; h < HEADS; ++h) {
                    bf16x4 aA = *(const bf16x4*)&s_amat[((tk * 4 + h) * 16 + col) * 16 + quad * 4];
                    acc = __builtin_amdgcn_mfma_f32_16x16x16bf16_1k(aA, Bb[tk][2 * h + s], acc, 0, 0, 0);
                }
                #pragma unroll
                for (int j = 0; j < 4; ++j) {
                    int m = quad * 4 + j;
                    if (m < R) {
                        float o = gelu_exact(acc[j] * 0.25f + bgv) + nf_frag[tk][s][j];
                        nf_frag[tk][s][j] = o;
                        if (l < NL - 1) s_nfb[(tk * 16 + m) * NFS + f] = f2bf(o);
                        else gf_out[(size_t)(tok0 + tk) * TOK + m * HID + f] = o;
                    }
                }
            }
        }
        __syncthreads();
    }
}

extern "C" void kernel_launch(void* const* d_in, const int* in_sizes, int n_in,
                              void* d_out, int out_size, void* d_ws, size_t ws_size,
                              hipStream_t stream) {
    const float* x      = (const float*)d_in[0];
    const float* Wenc   = (const float*)d_in[1];
    const float* benc   = (const float*)d_in[2];
    const float* gamma_ = (const float*)d_in[3];
    const float* beta_  = (const float*)d_in[4];
    const float* Wg     = (const float*)d_in[5];
    const float* asrc   = (const float*)d_in[6];
    const float* adst   = (const float*)d_in[7];
    const float* bg     = (const float*)d_in[8];
    const int*   srce   = (const int*)d_in[9];
    const int*   dste   = (const int*)d_in[10];

    const int E  = in_sizes[9];
    const int BT = in_sizes[0] / (R * C);   // 12800

    float* gf = (float*)d_out;
    float* rf = gf + (size_t)BT * TOK;
    short* Wcat = (short*)d_ws;             // NL*NCAT*HID bf16

    const int prep_total = NL * NCAT * HID;
    prep_wcat<<<(prep_total + 255) / 256, 256, 0, stream>>>(Wg, asrc, adst, Wcat);
    fused_gnn_mfma2<<<BT / 2, 256, 0, stream>>>(x, Wenc, benc, gamma_, beta_,
                                                Wcat, bg, srce, dste, gf, rf, E);
}

// Round 4
// 649.536 us; speedup vs baseline: 3.7246x; 3.7246x over previous
//
#include <hip/hip_runtime.h>
#include <hip/hip_bf16.h>
#include <math.h>

#define R 10
#define C 6
#define HID 128
#define HEADS 4
#define NL 3
#define KO 512            // HEADS*HID
#define TOK 1280          // R*HID
#define NCAT 544          // padded prep N: 512 xp + 8 logit cols
#define NFS 136           // s_nfb row stride (shorts)
#define HS 132            // s_nf row stride (floats)
#define AMS 20            // s_amat row stride (shorts): 40B rows, 8B-aligned, conflict-free
#define LN_EPS 1e-5f
#define NEG_SLOPE 0.2f
#define MAXE 40
#define MAXDEG 16

typedef __attribute__((ext_vector_type(8))) short short8v;  // 8 bf16 (x32 MFMA A/B)
typedef __attribute__((ext_vector_type(4))) short bf16x4;   // 4 bf16 (x16 MFMA A/B)
typedef __attribute__((ext_vector_type(4))) float floatx4;

__device__ __forceinline__ float gelu_exact(float v) {
    return 0.5f * v * (1.0f + erff(v * 0.70710678118654752440f));
}
__device__ __forceinline__ short f2bf(float v) {
    __hip_bfloat16 b = __float2bfloat16(v);
    return __builtin_bit_cast(short, b);
}

// ---- prep: Wcat[l][n][k] bf16, n-major k-contiguous ----
// n in [0,512): W^T columns; [512,516): W@asrc_h; [516,520): W@adst_h; rest 0.
__global__ void prep_wcat(const float* __restrict__ Wg,
                          const float* __restrict__ asrc,
                          const float* __restrict__ adst,
                          short* __restrict__ Wcat)
{
    int idx = blockIdx.x * 256 + threadIdx.x;
    const int TOTAL = NL * NCAT * HID;
    if (idx >= TOTAL) return;
    int k = idx & (HID - 1);
    int n = (idx >> 7) % NCAT;
    int l = idx / (NCAT * HID);
    float v = 0.f;
    if (n < KO) {
        v = Wg[((size_t)l * HID + k) * KO + n];
    } else if (n < KO + 8) {
        int h = (n - KO) & 3;
        const float* a = ((n - KO) < 4 ? asrc : adst) + (l * HEADS + h) * HID;
        const float* w = Wg + ((size_t)l * HID + k) * KO + h * HID;
        float s = 0.f;
        for (int f = 0; f < HID; ++f) s = fmaf(w[f], a[f], s);
        v = s;
    }
    Wcat[idx] = f2bf(v);
}

__global__ __launch_bounds__(256, 4) void fused_gnn_mfma3(
    const float* __restrict__ x,      // (BT, 60)
    const float* __restrict__ Wenc,   // (R, C, HID)
    const float* __restrict__ benc,   // (R, HID)
    const float* __restrict__ gamma_, // (R, HID)
    const float* __restrict__ beta_,  // (R, HID)
    const short* __restrict__ Wcat,   // (NL, NCAT, HID) bf16
    const float* __restrict__ bg,     // (NL, HID)
    const int* __restrict__ srce, const int* __restrict__ dste,
    float* __restrict__ gf_out, float* __restrict__ rf_out, int E)
{
    __shared__ __align__(16) short s_nfb[2 * 16 * NFS];          // 8.7 KB  bf16 nf, A-layout
    __shared__ __align__(16) float s_nf[2 * R * HS];             // 10.6 KB fp32 residual stream
    __shared__ __align__(16) short s_amat[2 * HEADS * 16 * AMS]; // 5.1 KB  alpha matrices bf16
    __shared__ float s_logit[2 * 16 * 8];                        // 1.0 KB
    __shared__ float s_x[120];
    __shared__ float s_mu[20], s_rs[20];
    __shared__ int s_src[MAXE], s_dst[MAXE], s_eid[R * MAXDEG], s_deg[R];

    const int t = threadIdx.x;
    const int lane = t & 63;
    const int w = t >> 6;          // wave
    const int quad = lane >> 4;
    const int col = lane & 15;
    const int tok0 = blockIdx.x * 2;

    // ---- prologue: zero s_nfb (rows 10-15 must stay 0), stage x + edges ----
    for (int i = t; i < (2 * 16 * NFS) / 2; i += 256) ((int*)s_nfb)[i] = 0;
    if (t < E) { s_src[t] = srce[t]; s_dst[t] = dste[t]; }
    if (t < 120) s_x[t] = x[(size_t)tok0 * 60 + t];
    __syncthreads();
    if (t < R) {
        int d = 0;
        for (int e = 0; e < E; ++e)
            if (s_dst[e] == t && d < MAXDEG) s_eid[t * MAXDEG + (d++)] = e;
        s_deg[t] = d;
    }

    // ---- encoder: h = x @ Wenc + benc -> s_nf ----
    for (int q = t; q < 640; q += 256) {
        int tk = q >= 320; int qq = q - tk * 320;
        int r = qq >> 5; int f4 = (qq & 31) << 2;
        const float* xr = &s_x[tk * 60 + r * 6];
        float4 acc = *(const float4*)&benc[r * HID + f4];
        #pragma unroll
        for (int c = 0; c < 6; ++c) {
            float xv = xr[c];
            float4 wv = *(const float4*)&Wenc[(r * 6 + c) * HID + f4];
            acc.x = fmaf(xv, wv.x, acc.x);
            acc.y = fmaf(xv, wv.y, acc.y);
            acc.z = fmaf(xv, wv.z, acc.z);
            acc.w = fmaf(xv, wv.w, acc.w);
        }
        *(float4*)&s_nf[(tk * R + r) * HS + f4] = acc;
    }
    __syncthreads();

    // ---- LayerNorm stats ----
    for (int rr = w; rr < 20; rr += 4) {
        const float* row = &s_nf[rr * HS];
        float v0 = row[lane], v1 = row[lane + 64];
        float sum = v0 + v1, sq = v0 * v0 + v1 * v1;
        #pragma unroll
        for (int off = 32; off > 0; off >>= 1) {
            sum += __shfl_down(sum, off);
            sq  += __shfl_down(sq,  off);
        }
        if (lane == 0) {
            float mu = sum * (1.0f / HID);
            float var = sq * (1.0f / HID) - mu * mu;
            s_mu[rr] = mu;
            s_rs[rr] = rsqrtf(var + LN_EPS);
        }
    }
    __syncthreads();

    // ---- normalize + affine + gelu -> s_nf (in place), s_nfb, rf_out ----
    for (int q = t; q < 640; q += 256) {
        int tk = q >= 320; int qq = q - tk * 320;
        int r = qq >> 5; int f4 = (qq & 31) << 2;
        float4 v = *(const float4*)&s_nf[(tk * R + r) * HS + f4];
        float mu = s_mu[tk * R + r], rs = s_rs[tk * R + r];
        float4 g = *(const float4*)&gamma_[r * HID + f4];
        float4 b = *(const float4*)&beta_[r * HID + f4];
        float4 o;
        o.x = gelu_exact((v.x - mu) * rs * g.x + b.x);
        o.y = gelu_exact((v.y - mu) * rs * g.y + b.y);
        o.z = gelu_exact((v.z - mu) * rs * g.z + b.z);
        o.w = gelu_exact((v.w - mu) * rs * g.w + b.w);
        *(float4*)&s_nf[(tk * R + r) * HS + f4] = o;
        short4 pk; pk.x = f2bf(o.x); pk.y = f2bf(o.y); pk.z = f2bf(o.z); pk.w = f2bf(o.w);
        *(short4*)&s_nfb[(tk * 16 + r) * NFS + f4] = pk;
        *(float4*)&rf_out[(size_t)(tok0 + tk) * TOK + qq * 4] = o;
    }
    __syncthreads();

    // ---- 3 GAT layers ----
    for (int l = 0; l < NL; ++l) {
        const short* __restrict__ Wl = Wcat + (size_t)l * NCAT * HID;

        // A fragments from s_nfb (A[m=lane&15][k=quad*8+j], k += 32/step)
        short8v aF[2][4];
        #pragma unroll
        for (int tk = 0; tk < 2; ++tk)
            #pragma unroll
            for (int ks = 0; ks < 4; ++ks)
                aF[tk][ks] = *(const short8v*)&s_nfb[(tk * 16 + col) * NFS + ks * 32 + quad * 8];

        // GEMM1: 8 xp tiles per wave, COMPILE-TIME register indexing (no scratch!)
        bf16x4 Bb[2][8];
        #pragma unroll
        for (int i = 0; i < 8; ++i) {
            const int nt = w + 4 * i;               // tiles 0..31, wave-strided
            const short* Bp = Wl + (nt * 16 + col) * HID + quad * 8;
            short8v b0 = *(const short8v*)(Bp);
            short8v b1 = *(const short8v*)(Bp + 32);
            short8v b2 = *(const short8v*)(Bp + 64);
            short8v b3 = *(const short8v*)(Bp + 96);
            #pragma unroll
            for (int tk = 0; tk < 2; ++tk) {
                floatx4 c = {0.f, 0.f, 0.f, 0.f};
                c = __builtin_amdgcn_mfma_f32_16x16x32_bf16(aF[tk][0], b0, c, 0, 0, 0);
                c = __builtin_amdgcn_mfma_f32_16x16x32_bf16(aF[tk][1], b1, c, 0, 0, 0);
                c = __builtin_amdgcn_mfma_f32_16x16x32_bf16(aF[tk][2], b2, c, 0, 0, 0);
                c = __builtin_amdgcn_mfma_f32_16x16x32_bf16(aF[tk][3], b3, c, 0, 0, 0);
                bf16x4 pk;
                pk[0] = f2bf(c[0]); pk[1] = f2bf(c[1]);
                pk[2] = f2bf(c[2]); pk[3] = f2bf(c[3]);
                Bb[tk][i] = pk;
            }
        }
        // logit tile (nt=32, cols 512-519): wave 0 only
        if (w == 0) {
            const short* Bp = Wl + (32 * 16 + col) * HID + quad * 8;
            short8v b0 = *(const short8v*)(Bp);
            short8v b1 = *(const short8v*)(Bp + 32);
            short8v b2 = *(const short8v*)(Bp + 64);
            short8v b3 = *(const short8v*)(Bp + 96);
            #pragma unroll
            for (int tk = 0; tk < 2; ++tk) {
                floatx4 c = {0.f, 0.f, 0.f, 0.f};
                c = __builtin_amdgcn_mfma_f32_16x16x32_bf16(aF[tk][0], b0, c, 0, 0, 0);
                c = __builtin_amdgcn_mfma_f32_16x16x32_bf16(aF[tk][1], b1, c, 0, 0, 0);
                c = __builtin_amdgcn_mfma_f32_16x16x32_bf16(aF[tk][2], b2, c, 0, 0, 0);
                c = __builtin_amdgcn_mfma_f32_16x16x32_bf16(aF[tk][3], b3, c, 0, 0, 0);
                if (col < 8) {
                    #pragma unroll
                    for (int j = 0; j < 4; ++j) {
                        int m = quad * 4 + j;
                        if (m < R) s_logit[tk * 128 + m * 8 + col] = c[j];
                    }
                }
            }
        }
        __syncthreads();

        // ---- softmax -> alpha matrices (bf16, padded row-major 16xAMS) ----
        if (t < 80) {
            int tk = t / 40; int rem = t - tk * 40;
            int r = rem >> 2; int h = rem & 3;
            short* arow = &s_amat[((tk * 4 + h) * 16 + r) * AMS];
            #pragma unroll
            for (int k = 0; k < 16; ++k) arow[k] = 0;
            float ald = s_logit[tk * 128 + r * 8 + 4 + h];
            int d = s_deg[r];
            float m = -1e30f;
            for (int k = 0; k < d; ++k) {
                int e = s_eid[r * MAXDEG + k];
                float val = s_logit[tk * 128 + s_src[e] * 8 + h] + ald;
                val = (val > 0.f) ? val : NEG_SLOPE * val;
                m = fmaxf(m, val);
            }
            float ssum = 0.f;
            for (int k = 0; k < d; ++k) {
                int e = s_eid[r * MAXDEG + k];
                float val = s_logit[tk * 128 + s_src[e] * 8 + h] + ald;
                val = (val > 0.f) ? val : NEG_SLOPE * val;
                ssum += expf(val - m);
            }
            float inv = 1.0f / ssum;
            for (int k = 0; k < d; ++k) {
                int e = s_eid[r * MAXDEG + k];
                float val = s_logit[tk * 128 + s_src[e] * 8 + h] + ald;
                val = (val > 0.f) ? val : NEG_SLOPE * val;
                arow[s_src[e]] = f2bf(expf(val - m) * inv);
            }
        } else if (t < 128) {                 // zero alpha rows 10-15
            int idx = t - 80;                 // 0..47
            int tk = idx / 24; int rem = idx % 24;
            int h = rem / 6; int r = 10 + rem % 6;
            short* arow = &s_amat[((tk * 4 + h) * 16 + r) * AMS];
            #pragma unroll
            for (int k = 0; k < 16; ++k) arow[k] = 0;
        }
        __syncthreads();

        // ---- MFMA2 aggregation (heads chained) + epilogue, residual via s_nf ----
        #pragma unroll
        for (int s = 0; s < 2; ++s) {
            int f = (w + 4 * s) * 16 + col;
            float bgv = bg[l * HID + f];
            #pragma unroll
            for (int tk = 0; tk < 2; ++tk) {
                floatx4 acc = {0.f, 0.f, 0.f, 0.f};
                #pragma unroll
                for (int h = 0; h < HEADS; ++h) {
                    bf16x4 aA = *(const bf16x4*)&s_amat[((tk * 4 + h) * 16 + col) * AMS + quad * 4];
                    acc = __builtin_amdgcn_mfma_f32_16x16x16bf16_1k(aA, Bb[tk][2 * h + s], acc, 0, 0, 0);
                }
                #pragma unroll
                for (int j = 0; j < 4; ++j) {
                    int m = quad * 4 + j;
                    if (m < R) {
                        float o = gelu_exact(acc[j] * 0.25f + bgv) + s_nf[(tk * R + m) * HS + f];
                        if (l < NL - 1) {
                            s_nf[(tk * R + m) * HS + f] = o;
                            s_nfb[(tk * 16 + m) * NFS + f] = f2bf(o);
                        } else {
                            gf_out[(size_t)(tok0 + tk) * TOK + m * HID + f] = o;
                        }
                    }
                }
            }
        }
        __syncthreads();
    }
}

extern "C" void kernel_launch(void* const* d_in, const int* in_sizes, int n_in,
                              void* d_out, int out_size, void* d_ws, size_t ws_size,
                              hipStream_t stream) {
    const float* x      = (const float*)d_in[0];
    const float* Wenc   = (const float*)d_in[1];
    const float* benc   = (const float*)d_in[2];
    const float* gamma_ = (const float*)d_in[3];
    const float* beta_  = (const float*)d_in[4];
    const float* Wg     = (const float*)d_in[5];
    const float* asrc   = (const float*)d_in[6];
    const float* adst   = (const float*)d_in[7];
    const float* bg     = (const float*)d_in[8];
    const int*   srce   = (const int*)d_in[9];
    const int*   dste   = (const int*)d_in[10];

    const int E  = in_sizes[9];
    const int BT = in_sizes[0] / (R * C);   // 12800

    float* gf = (float*)d_out;
    float* rf = gf + (size_t)BT * TOK;
    short* Wcat = (short*)d_ws;             // NL*NCAT*HID bf16

    const int prep_total = NL * NCAT * HID;
    prep_wcat<<<(prep_total + 255) / 256, 256, 0, stream>>>(Wg, asrc, adst, Wcat);
    fused_gnn_mfma3<<<BT / 2, 256, 0, stream>>>(x, Wenc, benc, gamma_, beta_,
                                                Wcat, bg, srce, dste, gf, rf, E);
}